// Round 2
// baseline (406.562 us; speedup 1.0000x reference)
//
#include <hip/hip_runtime.h>
#include <hip/hip_bf16.h>

#define B_ 32
#define S_ 2048
#define D_ 512
#define M_ (B_*S_)   // 65536 rows

typedef __bf16 bf16x8 __attribute__((ext_vector_type(8)));
typedef float  f32x4  __attribute__((ext_vector_type(4)));

__device__ __forceinline__ float tanh_fast(float x){
  float e2 = __expf(2.f * x);                    // inf for large x -> rcp=0 -> 1
  return 1.f - 2.f * __builtin_amdgcn_rcpf(e2 + 1.f);
}

// ---- reorder w_v (fp32 KxN row-major [e*512+d]) into bf16 MFMA B-frag order ----
// frag id f = ks*32 + nt. lane holds B[k = ks*32 + quad*8 + j][n = nt*16 + lm], j=0..7.
__global__ void k_reorder_wv(const float* __restrict__ wv,
                             unsigned short* __restrict__ wvr){
  int frag = blockIdx.x;          // 0..511
  int lane = threadIdx.x;         // 0..63
  int ks = frag >> 5, nt = frag & 31;
  int k0 = ks*32 + (lane>>4)*8;
  int d  = nt*16 + (lane&15);
  bf16x8 t;
  #pragma unroll
  for (int j=0;j<8;++j) t[j] = (__bf16)wv[(k0+j)*D_ + d];
  *reinterpret_cast<uint4*>(wvr + ((size_t)frag*64 + lane)*8) =
      __builtin_bit_cast(uint4, t);
}

// ---- qproj[b,d] = query[b,:] @ w_q[:,d] + bias[d]  (all fp32) ----
__global__ void k_qproj(const float* __restrict__ q,
                        const float* __restrict__ wq,
                        const float* __restrict__ bias,
                        float* __restrict__ qp){
  int b = blockIdx.y;
  int d = blockIdx.x*128 + threadIdx.x;
  __shared__ float qs[D_];
  for (int e=threadIdx.x; e<D_; e+=128) qs[e] = q[b*D_+e];
  __syncthreads();
  float acc = bias[d];
  #pragma unroll 4
  for (int e=0;e<D_;++e) acc = fmaf(qs[e], wq[e*D_+d], acc);
  qp[b*D_+d] = acc;
}

// ---- fused (value@w_v + qproj + loc) -> tanh -> dot(score_w) -> partial scores ----
// block = 256 = 4 waves, covers 64 rows (one batch; 64|2048). Wave w owns
// d in [w*128, (w+1)*128): 4 M-tiles x 8 N-tiles of 16x16x32 bf16 MFMA.
__launch_bounds__(256)
__global__ void k_energy(const float* __restrict__ value,
                         const unsigned short* __restrict__ wvr,
                         const float* __restrict__ qp,
                         const float* __restrict__ energy,
                         const float* __restrict__ conv_w,
                         const float* __restrict__ conv_b,
                         const float* __restrict__ score_w,
                         float* __restrict__ scores_part){
  const int wave = threadIdx.x >> 6;
  const int lane = threadIdx.x & 63;
  const int quad = lane >> 4;
  const int lm   = lane & 15;
  const int row0 = blockIdx.x * 64;
  const int b    = row0 >> 11;          // S=2048
  const int s0   = row0 & (S_-1);

  f32x4 acc[4][8];
  #pragma unroll
  for (int mt=0;mt<4;++mt)
    #pragma unroll
    for (int nt=0;nt<8;++nt)
      acc[mt][nt] = (f32x4){0.f,0.f,0.f,0.f};

  const float* aP = value + (size_t)(row0+lm)*D_ + quad*8;
  const unsigned short* bP = wvr + ((size_t)(wave*8)*64 + lane)*8;

  for (int ks=0; ks<16; ++ks){
    bf16x8 a[4];
    #pragma unroll
    for (int mt=0;mt<4;++mt){
      const float* p = aP + (size_t)mt*16*D_ + ks*32;
      f32x4 u0 = *reinterpret_cast<const f32x4*>(p);
      f32x4 u1 = *reinterpret_cast<const f32x4*>(p+4);
      bf16x8 t;
      t[0]=(__bf16)u0[0]; t[1]=(__bf16)u0[1]; t[2]=(__bf16)u0[2]; t[3]=(__bf16)u0[3];
      t[4]=(__bf16)u1[0]; t[5]=(__bf16)u1[1]; t[6]=(__bf16)u1[2]; t[7]=(__bf16)u1[3];
      a[mt] = t;
    }
    #pragma unroll
    for (int ntl=0; ntl<8; ++ntl){
      uint4 u = *reinterpret_cast<const uint4*>(bP + (size_t)(ks*32+ntl)*64*8);
      bf16x8 bf = __builtin_bit_cast(bf16x8, u);
      #pragma unroll
      for (int mt=0;mt<4;++mt)
        acc[mt][ntl] = __builtin_amdgcn_mfma_f32_16x16x32_bf16(a[mt], bf, acc[mt][ntl], 0,0,0);
    }
  }

  // epilogue: per-lane d set = wave*128 + ntl*16 + lm (fp32 aux)
  float sw[8], c0[8], c1[8], c2[8], cb[8], qv[8];
  #pragma unroll
  for (int ntl=0; ntl<8; ++ntl){
    int d = wave*128 + ntl*16 + lm;
    sw[ntl] = score_w[d];
    c0[ntl] = conv_w[d*3+0];
    c1[ntl] = conv_w[d*3+1];
    c2[ntl] = conv_w[d*3+2];
    cb[ntl] = conv_b[d];
    qv[ntl] = qp[b*D_+d];
  }
  const float* eB = energy + b*S_;
  #pragma unroll
  for (int mt=0; mt<4; ++mt){
    #pragma unroll
    for (int r=0;r<4;++r){
      int s = s0 + mt*16 + quad*4 + r;          // C/D layout: row=quad*4+reg
      float em1 = (s > 0)    ? eB[s-1] : 0.f;
      float e0  =              eB[s];
      float ep1 = (s < S_-1) ? eB[s+1] : 0.f;
      float p = 0.f;
      #pragma unroll
      for (int ntl=0; ntl<8; ++ntl){
        float h = acc[mt][ntl][r] + qv[ntl]
                + fmaf(c0[ntl],em1, fmaf(c1[ntl],e0, fmaf(c2[ntl],ep1, cb[ntl])));
        p = fmaf(sw[ntl], tanh_fast(h), p);
      }
      #pragma unroll
      for (int m=1; m<16; m<<=1) p += __shfl_xor(p, m, 64);   // reduce 16 cols
      if (lm == 0)
        scores_part[wave*M_ + row0 + mt*16 + quad*4 + r] = p;
    }
  }
}

// ---- softmax over S per batch; align written straight to d_out (fp32) ----
__global__ void k_softmax(const float* __restrict__ sp,
                          const float* __restrict__ score_b,
                          float* __restrict__ out_align){
  int b = blockIdx.x, t = threadIdx.x;
  int lane = t & 63, wid = t >> 6;
  float sb = score_b[0];
  float v[8], mx = -3.4e38f;
  #pragma unroll
  for (int i=0;i<8;++i){
    int s = t + i*256;
    float sc = sp[0*M_+b*S_+s] + sp[1*M_+b*S_+s] + sp[2*M_+b*S_+s] + sp[3*M_+b*S_+s] + sb;
    v[i] = sc;
    mx = fmaxf(mx, sc);
  }
  __shared__ float red[4], red2[4];
  #pragma unroll
  for (int m=1;m<64;m<<=1) mx = fmaxf(mx, __shfl_xor(mx, m, 64));
  if (lane==0) red[wid] = mx;
  __syncthreads();
  mx = fmaxf(fmaxf(red[0],red[1]), fmaxf(red[2],red[3]));
  float sum = 0.f;
  #pragma unroll
  for (int i=0;i<8;++i){ v[i] = __expf(v[i]-mx); sum += v[i]; }
  #pragma unroll
  for (int m=1;m<64;m<<=1) sum += __shfl_xor(sum, m, 64);
  if (lane==0) red2[wid] = sum;
  __syncthreads();
  sum = red2[0]+red2[1]+red2[2]+red2[3];
  float inv = 1.f/sum;
  #pragma unroll
  for (int i=0;i<8;++i) out_align[b*S_ + t + i*256] = v[i]*inv;
}

// ---- context partials: block (sc,b) covers 128 s rows; float4 loads ----
__global__ void k_ctx_part(const float* __restrict__ value,
                           const float* __restrict__ align,
                           float* __restrict__ cpart){
  int b = blockIdx.y, sc = blockIdx.x;
  int t = threadIdx.x;
  int r = t >> 7;            // 0..1 (s subgroup)
  int c = (t & 127) * 4;     // d base, 4 floats = 16B per thread
  f32x4 acc = (f32x4){0.f,0.f,0.f,0.f};
  for (int i=0;i<64;++i){
    int s = sc*128 + i*2 + r;
    float al = align[b*S_+s];
    f32x4 v = *reinterpret_cast<const f32x4*>(value + ((size_t)(b*S_+s))*D_ + c);
    acc += al * v;
  }
  __shared__ float lred[2][D_];
  #pragma unroll
  for (int j=0;j<4;++j) lred[r][c+j] = acc[j];
  __syncthreads();
  if (r == 0){
    #pragma unroll
    for (int j=0;j<4;++j)
      cpart[((size_t)(b*16+sc))*D_ + c + j] = lred[0][c+j] + lred[1][c+j];
  }
}

__global__ void k_ctx_reduce(const float* __restrict__ cpart,
                             float* __restrict__ out_ctx){
  int idx = blockIdx.x*256 + threadIdx.x;   // 0..16383
  int b = idx >> 9, d = idx & 511;
  float s = 0.f;
  #pragma unroll
  for (int j=0;j<16;++j) s += cpart[((size_t)(b*16+j))*D_ + d];
  out_ctx[idx] = s;
}

extern "C" void kernel_launch(void* const* d_in, const int* in_sizes, int n_in,
                              void* d_out, int out_size, void* d_ws, size_t ws_size,
                              hipStream_t stream){
  const float* query   = (const float*)d_in[0];
  const float* value   = (const float*)d_in[1];
  const float* energy  = (const float*)d_in[2];
  const float* conv_w  = (const float*)d_in[3];
  const float* conv_b  = (const float*)d_in[4];
  const float* w_q     = (const float*)d_in[5];
  const float* w_v     = (const float*)d_in[6];
  const float* bias    = (const float*)d_in[7];
  const float* score_w = (const float*)d_in[8];
  const float* score_b = (const float*)d_in[9];

  char* ws = (char*)d_ws;
  unsigned short* wvr = (unsigned short*)(ws);            // 512 KB (bf16 frags)
  float* qp    = (float*)(ws + (512<<10));                // 64 KB
  float* sp    = (float*)(ws + (576<<10));                // 1 MB (4 x 65536 f32)
  float* cpart = (float*)(ws + (1600<<10));               // 1 MB (16 x 32 x 512 f32)
  // total ~2.6 MB

  float* out_ctx   = (float*)d_out;                       // [B, D] fp32
  float* out_align = out_ctx + B_*D_;                     // [B, S] fp32

  k_reorder_wv<<<dim3(512),      dim3(64),  0, stream>>>(w_v, wvr);
  k_qproj     <<<dim3(4,32),     dim3(128), 0, stream>>>(query, w_q, bias, qp);
  k_energy    <<<dim3(M_/64),    dim3(256), 0, stream>>>(value, wvr, qp, energy,
                                                         conv_w, conv_b, score_w, sp);
  k_softmax   <<<dim3(B_),       dim3(256), 0, stream>>>(sp, score_b, out_align);
  k_ctx_part  <<<dim3(16,B_),    dim3(256), 0, stream>>>(value, out_align, cpart);
  k_ctx_reduce<<<dim3(B_*D_/256),dim3(256), 0, stream>>>(cpart, out_ctx);
}

// Round 3
// 287.327 us; speedup vs baseline: 1.4150x; 1.4150x over previous
//
#include <hip/hip_runtime.h>
#include <hip/hip_bf16.h>

#define B_ 32
#define S_ 2048
#define D_ 512
#define M_ (B_*S_)   // 65536 rows

typedef __bf16 bf16x8 __attribute__((ext_vector_type(8)));
typedef float  f32x4  __attribute__((ext_vector_type(4)));

__device__ __forceinline__ float tanh_fast(float x){
  float e2 = __expf(2.f * x);                    // inf for large x -> rcp=0 -> 1
  return 1.f - 2.f * __builtin_amdgcn_rcpf(e2 + 1.f);
}

// ---- reorder w_v (fp32 KxN row-major [e*512+d]) into bf16 MFMA B-frag order ----
// frag id f = ks*32 + nt. lane holds B[k = ks*32 + quad*8 + j][n = nt*16 + lm], j=0..7.
__global__ void k_reorder_wv(const float* __restrict__ wv,
                             unsigned short* __restrict__ wvr){
  int frag = blockIdx.x;          // 0..511
  int lane = threadIdx.x;         // 0..63
  int ks = frag >> 5, nt = frag & 31;
  int k0 = ks*32 + (lane>>4)*8;
  int d  = nt*16 + (lane&15);
  bf16x8 t;
  #pragma unroll
  for (int j=0;j<8;++j) t[j] = (__bf16)wv[(k0+j)*D_ + d];
  *reinterpret_cast<uint4*>(wvr + ((size_t)frag*64 + lane)*8) =
      __builtin_bit_cast(uint4, t);
}

// ---- qproj[b,d] = query[b,:] @ w_q[:,d] + bias[d]  (fp32, 4-way K-split) ----
__global__ void k_qproj(const float* __restrict__ q,
                        const float* __restrict__ wq,
                        const float* __restrict__ bias,
                        float* __restrict__ qp){
  int b  = blockIdx.y;
  int t  = threadIdx.x;          // 512
  int dl = t & 127, eg = t >> 7;
  int d  = blockIdx.x*128 + dl;
  __shared__ float qs[D_];
  __shared__ float red[4][128];
  for (int e=t; e<D_; e+=512) qs[e] = q[b*D_+e];
  __syncthreads();
  float acc = 0.f;
  #pragma unroll 8
  for (int i=0;i<128;++i){
    int e = eg*128 + i;
    acc = fmaf(qs[e], wq[(size_t)e*D_+d], acc);
  }
  red[eg][dl] = acc;
  __syncthreads();
  if (eg == 0)
    qp[b*D_+d] = red[0][dl]+red[1][dl]+red[2][dl]+red[3][dl] + bias[d];
}

// ---- fused (value@w_v + qproj + loc) -> tanh -> dot(score_w) -> scores ----
// 256 thr = 4 waves, block covers 64 rows (one batch; 64|2048). Wave w owns
// d in [w*128,(w+1)*128): 4 M-tiles x 8 N-tiles of 16x16x32 bf16 MFMA.
// A staged in LDS (bf16, frag order, double-buffered); B direct from L2.
__launch_bounds__(256, 2)
__global__ void k_energy(const float* __restrict__ value,
                         const unsigned short* __restrict__ wvr,
                         const float* __restrict__ qp,
                         const float* __restrict__ energy,
                         const float* __restrict__ conv_w,
                         const float* __restrict__ conv_b,
                         const float* __restrict__ score_w,
                         float* __restrict__ scores){
  const int t    = threadIdx.x;
  const int wave = t >> 6;
  const int lane = t & 63;
  const int quad = lane >> 4;
  const int lm   = lane & 15;
  const int row0 = blockIdx.x * 64;
  const int b    = row0 >> 11;          // S=2048
  const int s0   = row0 & (S_-1);

  // As[buf][mt][o*16+lm][8]: frag-ordered A chunk (64 rows x 32 k bf16) = 4 KB/buf
  __shared__ __align__(16) unsigned short As[2][4][64][8];

  // staging mapping: thread t -> row sr = t>>2, k-octet so = t&3
  const int sr  = t >> 2;
  const int so  = t & 3;
  const float* gA = value + (size_t)(row0+sr)*D_ + so*8;
  unsigned short* wA = &As[0][sr>>4][so*16 + (sr&15)][0];

  f32x4 acc[4][8];
  #pragma unroll
  for (int mt=0;mt<4;++mt)
    #pragma unroll
    for (int nt=0;nt<8;++nt)
      acc[mt][nt] = (f32x4){0.f,0.f,0.f,0.f};

  const unsigned short* bP = wvr + ((size_t)(wave*8)*64 + lane)*8;

  // prologue: stage chunk 0 into buf 0
  {
    f32x4 p0 = *reinterpret_cast<const f32x4*>(gA);
    f32x4 p1 = *reinterpret_cast<const f32x4*>(gA+4);
    bf16x8 tt;
    tt[0]=(__bf16)p0[0]; tt[1]=(__bf16)p0[1]; tt[2]=(__bf16)p0[2]; tt[3]=(__bf16)p0[3];
    tt[4]=(__bf16)p1[0]; tt[5]=(__bf16)p1[1]; tt[6]=(__bf16)p1[2]; tt[7]=(__bf16)p1[3];
    *reinterpret_cast<uint4*>(wA) = __builtin_bit_cast(uint4, tt);
  }
  __syncthreads();

  for (int kc=0; kc<16; ++kc){
    const int buf = kc & 1;
    f32x4 n0, n1;
    if (kc < 15){
      n0 = *reinterpret_cast<const f32x4*>(gA + (kc+1)*32);
      n1 = *reinterpret_cast<const f32x4*>(gA + (kc+1)*32 + 4);
    }
    bf16x8 a[4];
    #pragma unroll
    for (int mt=0;mt<4;++mt)
      a[mt] = *reinterpret_cast<const bf16x8*>(&As[buf][mt][lane][0]);
    bf16x8 bfr[8];
    #pragma unroll
    for (int ntl=0;ntl<8;++ntl)
      bfr[ntl] = __builtin_bit_cast(bf16x8,
        *reinterpret_cast<const uint4*>(bP + (size_t)(kc*32+ntl)*64*8));
    #pragma unroll
    for (int ntl=0;ntl<8;++ntl)
      #pragma unroll
      for (int mt=0;mt<4;++mt)
        acc[mt][ntl] = __builtin_amdgcn_mfma_f32_16x16x32_bf16(a[mt], bfr[ntl], acc[mt][ntl], 0,0,0);
    if (kc < 15){
      bf16x8 tt;
      tt[0]=(__bf16)n0[0]; tt[1]=(__bf16)n0[1]; tt[2]=(__bf16)n0[2]; tt[3]=(__bf16)n0[3];
      tt[4]=(__bf16)n1[0]; tt[5]=(__bf16)n1[1]; tt[6]=(__bf16)n1[2]; tt[7]=(__bf16)n1[3];
      *reinterpret_cast<uint4*>(wA + (buf^1)*2048) = __builtin_bit_cast(uint4, tt);
    }
    __syncthreads();
  }

  // epilogue: per-lane d set = wave*128 + ntl*16 + lm
  float sw[8], c0[8], c1[8], c2[8], cb[8], qv[8];
  #pragma unroll
  for (int ntl=0; ntl<8; ++ntl){
    int d = wave*128 + ntl*16 + lm;
    sw[ntl] = score_w[d];
    c0[ntl] = conv_w[d*3+0];
    c1[ntl] = conv_w[d*3+1];
    c2[ntl] = conv_w[d*3+2];
    cb[ntl] = conv_b[d];
    qv[ntl] = qp[b*D_+d];
  }
  float* red = (float*)&As[0][0][0][0];   // reuse LDS: 4 waves x 64 rows
  const float* eB = energy + b*S_;
  #pragma unroll
  for (int mt=0; mt<4; ++mt){
    #pragma unroll
    for (int r=0;r<4;++r){
      int sl = mt*16 + quad*4 + r;              // C/D layout: row=quad*4+reg
      int s  = s0 + sl;
      float em1 = (s > 0)    ? eB[s-1] : 0.f;
      float e0  =              eB[s];
      float ep1 = (s < S_-1) ? eB[s+1] : 0.f;
      float p = 0.f;
      #pragma unroll
      for (int ntl=0; ntl<8; ++ntl){
        float h = acc[mt][ntl][r] + qv[ntl]
                + fmaf(c0[ntl],em1, fmaf(c1[ntl],e0, fmaf(c2[ntl],ep1, cb[ntl])));
        p = fmaf(sw[ntl], tanh_fast(h), p);
      }
      #pragma unroll
      for (int m=1; m<16; m<<=1) p += __shfl_xor(p, m, 64);   // reduce 16 cols
      if (lm == 0) red[wave*64 + sl] = p;
    }
  }
  __syncthreads();
  if (t < 64)
    scores[row0 + t] = red[t] + red[64+t] + red[128+t] + red[192+t];
}

// ---- softmax over S per batch; align written straight to d_out (fp32) ----
__global__ void k_softmax(const float* __restrict__ sp,
                          const float* __restrict__ score_b,
                          float* __restrict__ out_align){
  int b = blockIdx.x, t = threadIdx.x;
  int lane = t & 63, wid = t >> 6;
  float sb = score_b[0];
  float v[8], mx = -3.4e38f;
  #pragma unroll
  for (int i=0;i<8;++i){
    float sc = sp[b*S_ + t + i*256] + sb;
    v[i] = sc;
    mx = fmaxf(mx, sc);
  }
  __shared__ float red[4], red2[4];
  #pragma unroll
  for (int m=1;m<64;m<<=1) mx = fmaxf(mx, __shfl_xor(mx, m, 64));
  if (lane==0) red[wid] = mx;
  __syncthreads();
  mx = fmaxf(fmaxf(red[0],red[1]), fmaxf(red[2],red[3]));
  float sum = 0.f;
  #pragma unroll
  for (int i=0;i<8;++i){ v[i] = __expf(v[i]-mx); sum += v[i]; }
  #pragma unroll
  for (int m=1;m<64;m<<=1) sum += __shfl_xor(sum, m, 64);
  if (lane==0) red2[wid] = sum;
  __syncthreads();
  sum = red2[0]+red2[1]+red2[2]+red2[3];
  float inv = 1.f/sum;
  #pragma unroll
  for (int i=0;i<8;++i) out_align[b*S_ + t + i*256] = v[i]*inv;
}

// ---- context partials: block (sc,b) covers 128 s rows; float4 loads ----
__global__ void k_ctx_part(const float* __restrict__ value,
                           const float* __restrict__ align,
                           float* __restrict__ cpart){
  int b = blockIdx.y, sc = blockIdx.x;
  int t = threadIdx.x;
  int r = t >> 7;            // 0..1 (s subgroup)
  int c = (t & 127) * 4;     // d base, 4 floats = 16B per thread
  f32x4 acc = (f32x4){0.f,0.f,0.f,0.f};
  for (int i=0;i<64;++i){
    int s = sc*128 + i*2 + r;
    float al = align[b*S_+s];
    f32x4 v = *reinterpret_cast<const f32x4*>(value + ((size_t)(b*S_+s))*D_ + c);
    acc += al * v;
  }
  __shared__ float lred[2][D_];
  #pragma unroll
  for (int j=0;j<4;++j) lred[r][c+j] = acc[j];
  __syncthreads();
  if (r == 0){
    #pragma unroll
    for (int j=0;j<4;++j)
      cpart[((size_t)(b*16+sc))*D_ + c + j] = lred[0][c+j] + lred[1][c+j];
  }
}

__global__ void k_ctx_reduce(const float* __restrict__ cpart,
                             float* __restrict__ out_ctx){
  int idx = blockIdx.x*256 + threadIdx.x;   // 0..16383
  int b = idx >> 9, d = idx & 511;
  float s = 0.f;
  #pragma unroll
  for (int j=0;j<16;++j) s += cpart[((size_t)(b*16+j))*D_ + d];
  out_ctx[idx] = s;
}

extern "C" void kernel_launch(void* const* d_in, const int* in_sizes, int n_in,
                              void* d_out, int out_size, void* d_ws, size_t ws_size,
                              hipStream_t stream){
  const float* query   = (const float*)d_in[0];
  const float* value   = (const float*)d_in[1];
  const float* energy  = (const float*)d_in[2];
  const float* conv_w  = (const float*)d_in[3];
  const float* conv_b  = (const float*)d_in[4];
  const float* w_q     = (const float*)d_in[5];
  const float* w_v     = (const float*)d_in[6];
  const float* bias    = (const float*)d_in[7];
  const float* score_w = (const float*)d_in[8];
  const float* score_b = (const float*)d_in[9];

  char* ws = (char*)d_ws;
  unsigned short* wvr = (unsigned short*)(ws);            // 512 KB (bf16 frags)
  float* qp    = (float*)(ws + (512<<10));                // 64 KB
  float* sp    = (float*)(ws + (576<<10));                // 256 KB (65536 f32)
  float* cpart = (float*)(ws + (832<<10));                // 1 MB (16 x 32 x 512 f32)
  // total ~1.85 MB

  float* out_ctx   = (float*)d_out;                       // [B, D] fp32
  float* out_align = out_ctx + B_*D_;                     // [B, S] fp32

  k_reorder_wv<<<dim3(512),      dim3(64),  0, stream>>>(w_v, wvr);
  k_qproj     <<<dim3(4,32),     dim3(512), 0, stream>>>(query, w_q, bias, qp);
  k_energy    <<<dim3(M_/64),    dim3(256), 0, stream>>>(value, wvr, qp, energy,
                                                         conv_w, conv_b, score_w, sp);
  k_softmax   <<<dim3(B_),       dim3(256), 0, stream>>>(sp, score_b, out_align);
  k_ctx_part  <<<dim3(16,B_),    dim3(256), 0, stream>>>(value, out_align, cpart);
  k_ctx_reduce<<<dim3(B_*D_/256),dim3(256), 0, stream>>>(cpart, out_ctx);
}